// Round 2
// baseline (4044.762 us; speedup 1.0000x reference)
//
#include <hip/hip_runtime.h>
#include <math.h>

// Problem constants (from reference)
#define BSZ 4096
#define HL  20
#define NF  128
#define DM  640      // 3*NF + EF + TF
#define DIN 512      // DM - TF
#define DH  320      // DM / NHEAD

static __device__ __forceinline__ float sigmoidf_(float x){ return 1.f/(1.f+expf(-x)); }

// ---------------------------------------------------------------------------
// T1: combT[jc*128+jq] = (outfn_w @ out_proj_w)[jq, jc]
// grid 640, block 128
__global__ void k_comb(const float* __restrict__ outfn_w,
                       const float* __restrict__ out_proj_w,
                       float* __restrict__ combT)
{
    int jc = blockIdx.x, jq = threadIdx.x;
    float acc = 0.f;
    for (int e = 0; e < DM; ++e)
        acc += outfn_w[jq*DM + e] * out_proj_w[e*DM + jc];
    combT[jc*NF + jq] = acc;
}

// T2: ZZ[ef*128+jq]
// grid 1280, block 128
__global__ void k_zz(const float* __restrict__ in_proj_w,
                     const float* __restrict__ combT,
                     float* __restrict__ ZZ)
{
    int ef = blockIdx.x;
    int h = ef / DM, e = ef - h*DM;
    int jq = threadIdx.x;
    const float* wv = in_proj_w + (2*DM + h*DH)*DM + e;   // + dd*DM
    const float* cb = combT + (h*DH)*NF + jq;             // + dd*NF
    float acc = 0.f;
    for (int dd = 0; dd < DH; ++dd)
        acc += wv[dd*DM] * cb[dd*NF];
    ZZ[ef*NF + jq] = acc;
}

// T3: qbias
// grid 1, block 128
__global__ void k_qbias(const float* __restrict__ outfn_b,
                        const float* __restrict__ out_proj_b,
                        const float* __restrict__ outfn_w,
                        const float* __restrict__ in_proj_b,
                        const float* __restrict__ combT,
                        float* __restrict__ qb)
{
    int jq = threadIdx.x;
    float acc = outfn_b[jq];
    for (int e = 0; e < DM; ++e)  acc += out_proj_b[e] * outfn_w[jq*DM + e];
    for (int jc = 0; jc < DM; ++jc) acc += in_proj_b[2*DM + jc] * combT[jc*NF + jq];
    qb[jq] = acc;
}

// T4: transposes
// grid 960, block 256
__global__ void k_transpose(const float* __restrict__ gih,
                            const float* __restrict__ ghh,
                            float* __restrict__ giT,
                            float* __restrict__ ghT)
{
    int i = blockIdx.x*blockDim.x + threadIdx.x;
    if (i < DIN*3*NF) {
        int d = i / (3*NF), j = i - d*(3*NF);
        giT[i] = gih[j*DIN + d];
    } else {
        int i2 = i - DIN*3*NF;
        int d = i2 / (3*NF), j = i2 - d*(3*NF);
        ghT[i2] = ghh[j*NF + d];
    }
}

// K2a: qc[j]
// grid 5, block 128
__global__ void k_qc(const float* __restrict__ time_b,
                     const float* __restrict__ in_proj_w,
                     const float* __restrict__ in_proj_b,
                     float* __restrict__ qcv)
{
    __shared__ float tsr[NF];
    int tid = threadIdx.x;
    tsr[tid] = cosf(time_b[tid]);
    __syncthreads();
    int j = blockIdx.x*128 + tid;
    const float* wr = in_proj_w + j*DM + DIN;
    float acc = in_proj_b[j];
    for (int d = 0; d < NF; ++d) acc += tsr[d]*wr[d];
    qcv[j] = acc;
}

// K2a2: cc[h]
// grid 1, block 128
__global__ void k_cc(const float* __restrict__ qcv,
                     const float* __restrict__ in_proj_b,
                     float* __restrict__ cc)
{
    int wave = threadIdx.x >> 6, lane = threadIdx.x & 63;
    float acc = 0.f;
    for (int j = lane; j < DH; j += 64)
        acc += qcv[wave*DH + j] * in_proj_b[DM + wave*DH + j];
    for (int off = 32; off > 0; off >>= 1) acc += __shfl_down(acc, off);
    if (lane == 0) cc[wave] = acc;
}

// K2b: u
// grid 20, block 64
__global__ void k_u(const float* __restrict__ qcv,
                    const float* __restrict__ in_proj_w,
                    float* __restrict__ u)
{
    int d = blockIdx.x*64 + threadIdx.x;
    int h = d / DM, dd = d - h*DM;
    const float* base = in_proj_w + (DM + h*DH)*DM + dd;
    const float* q = qcv + h*DH;
    float acc = 0.f;
    for (int j = 0; j < DH; ++j) acc += q[j]*base[j*DM];
    u[d] = acc;
}

// ---------------------------------------------------------------------------
// K3: per-batch fused build + MHA attention (collapsed form).
// grid 4096, block 256
__global__ __launch_bounds__(256) void k_attn1(
    const int* __restrict__ nids, const int* __restrict__ hist_nids,
    const int* __restrict__ aidsp, const int* __restrict__ eidsp,
    const float* __restrict__ hist_ts, const int* __restrict__ dirsp,
    const float* __restrict__ node_feat, const float* __restrict__ edge_feat,
    const float* __restrict__ anony_emb,
    const float* __restrict__ time_w, const float* __restrict__ time_b,
    const float* __restrict__ u, const float* __restrict__ cc,
    float* __restrict__ wbuf, float* __restrict__ lef)
{
    int b = blockIdx.x, tid = threadIdx.x;
    __shared__ float zf[HL][DM];      // 51.2 KB
    __shared__ float ul[2*DM];
    __shared__ float sc[2][HL];
    __shared__ float aw[2][HL];
    __shared__ int   shn[HL], sdir[HL], said[HL], seid[HL];
    __shared__ float sts[HL];

    if (tid < HL) {
        shn[tid]  = hist_nids[b*HL+tid];
        sdir[tid] = dirsp[b*HL+tid];
        said[tid] = aidsp[b*HL+tid];
        seid[tid] = eidsp[b*HL+tid];
        sts[tid]  = hist_ts[b*HL+tid];
    }
    for (int i = tid; i < 2*DM; i += 256) ul[i] = u[i];
    __syncthreads();

    int rnid = nids[b];
    float tlast = sts[HL-1];
    for (int l = 0; l < HL; ++l) {
        int hn = shn[l], dir = sdir[l];
        int srcn = dir ? rnid : hn;
        int dstn = dir ? hn : rnid;
        int aid = said[l], eid = seid[l];
        float dt = tlast - sts[l];
        for (int c = tid; c < DM; c += 256) {
            float v;
            if (c < NF)            v = node_feat[srcn*NF + c];
            else if (c < 2*NF)     v = node_feat[dstn*NF + (c-NF)];
            else if (c < 3*NF)     v = anony_emb[aid*NF + (c-2*NF)];
            else if (c < 4*NF)     v = edge_feat[eid*NF + (c-3*NF)];
            else { int d = c - 4*NF; v = cosf(dt*time_w[d] + time_b[d]); }
            if (l == HL-1 && c < DIN) { lef[b*DIN + c] = v; v = 0.f; }
            zf[l][c] = v;
        }
    }
    __syncthreads();

    int wave = tid >> 6, lane = tid & 63;
    float c0 = cc[0], c1 = cc[1];
    for (int pr = wave; pr < 2*HL; pr += 4) {
        int h = pr / HL, m = pr - h*HL;
        float acc = 0.f;
        for (int d = lane; d < DM; d += 64) acc += ul[h*DM + d]*zf[m][d];
        for (int off = 32; off > 0; off >>= 1) acc += __shfl_down(acc, off);
        if (lane == 0) {
            float s = (acc + (h ? c1 : c0)) * 0.05590169943749474f; // 1/sqrt(320)
            bool msk = (shn[m] == 0) && (m != HL-1);
            sc[h][m] = msk ? -1.0e9f : s;
        }
    }
    __syncthreads();
    if (tid < 2) {
        float mx = -3.0e38f;
        for (int m = 0; m < HL; ++m) mx = fmaxf(mx, sc[tid][m]);
        float sum = 0.f;
        for (int m = 0; m < HL; ++m) { float e = expf(sc[tid][m]-mx); aw[tid][m] = e; sum += e; }
        float inv = 1.f/sum;
        for (int m = 0; m < HL; ++m) aw[tid][m] *= inv;
    }
    __syncthreads();
    for (int i = tid; i < 2*DM; i += 256) {
        int h = i / DM, d = i - h*DM;
        float acc = 0.f;
        #pragma unroll
        for (int m = 0; m < HL; ++m) acc += aw[h][m]*zf[m][d];
        wbuf[b*2*DM + i] = acc;
    }
}

// ---------------------------------------------------------------------------
// Row-block GEMM: qn = wbuf @ ZZ + qbias
__global__ __launch_bounds__(256) void k_gemm_qn(const float* __restrict__ A,
                                                 const float* __restrict__ BT,
                                                 const float* __restrict__ bias,
                                                 float* __restrict__ C)
{
    constexpr int K = 2*DM;  // 1280
    __shared__ float As[8*K];   // 40 KB
    int r0 = blockIdx.x*8, tid = threadIdx.x;
    for (int i = tid; i < 8*K; i += 256) As[i] = A[r0*K + i];
    __syncthreads();
    int j = tid & (NF-1), rh = tid >> 7;
    const float* bp = BT + j;
    const float* ap = As + rh*4*K;
    float acc0=0.f, acc1=0.f, acc2=0.f, acc3=0.f;
    for (int d = 0; d < K; ++d) {
        float bv = bp[d*NF];
        acc0 += ap[d]*bv;
        acc1 += ap[K + d]*bv;
        acc2 += ap[2*K + d]*bv;
        acc3 += ap[3*K + d]*bv;
    }
    float bsv = bias[j];
    int rb = r0 + rh*4;
    C[(rb+0)*NF + j] = acc0 + bsv;
    C[(rb+1)*NF + j] = acc1 + bsv;
    C[(rb+2)*NF + j] = acc2 + bsv;
    C[(rb+3)*NF + j] = acc3 + bsv;
}

// Row-block GEMM: gi = lef @ giT + gru_b_ih
__global__ __launch_bounds__(256) void k_gemm_gi(const float* __restrict__ A,
                                                 const float* __restrict__ BT,
                                                 const float* __restrict__ bias,
                                                 float* __restrict__ C)
{
    constexpr int K = DIN;     // 512
    constexpr int N = 3*NF;    // 384
    __shared__ float As[8*K];  // 16 KB
    int r0 = blockIdx.x*8, tid = threadIdx.x;
    for (int i = tid; i < 8*K; i += 256) As[i] = A[r0*K + i];
    __syncthreads();
    int j0 = tid, j1 = tid + 256;
    bool has1 = (j1 < N);
    float a0[8] = {0,0,0,0,0,0,0,0};
    float a1[8] = {0,0,0,0,0,0,0,0};
    for (int d = 0; d < K; ++d) {
        float b0 = BT[d*N + j0];
        float b1 = 0.f;
        if (has1) b1 = BT[d*N + j1];
        #pragma unroll
        for (int r = 0; r < 8; ++r) {
            float av = As[r*K + d];
            a0[r] += av*b0;
            a1[r] += av*b1;
        }
    }
    float bs0 = bias[j0];
    for (int r = 0; r < 8; ++r) C[(r0+r)*N + j0] = a0[r] + bs0;
    if (has1) {
        float bs1 = bias[j1];
        for (int r = 0; r < 8; ++r) C[(r0+r)*N + j1] = a1[r] + bs1;
    }
}

// ---------------------------------------------------------------------------
// K4: attention2 (collapsed) + merge + GRU.  grid 4096, block 128.
// nb[l] rows are NOT staged in LDS (re-gathered from global, L2/L3-resident)
// so LDS stays ~4 KB -> high occupancy hides the serial matvec chain.
__global__ __launch_bounds__(128) void k_attn2(
    const int* __restrict__ nids, const int* __restrict__ hist_nids,
    const int* __restrict__ eidsp, const float* __restrict__ hist_ts,
    const float* __restrict__ node_feat, const float* __restrict__ edge_feat,
    const float* __restrict__ time_w, const float* __restrict__ time_b,
    const float* __restrict__ attn_wq, const float* __restrict__ attn_wk,
    const float* __restrict__ attn_wv,
    const float* __restrict__ merge_w, const float* __restrict__ merge_b,
    const float* __restrict__ qn, const float* __restrict__ gi,
    const float* __restrict__ ghT, const float* __restrict__ gru_b_hh,
    float* __restrict__ hpr_out, float* __restrict__ out)
{
    int b = blockIdx.x, tid = threadIdx.x;
    __shared__ float qns[NF], qh[NF], p[3*NF], nbar[3*NF];
    __shared__ float scl[HL], al[HL];
    __shared__ float ctx2[NF], hpl[NF], nfn[NF];
    __shared__ int   shn[HL], seid[HL];
    __shared__ float sts[HL];

    if (tid < HL) {
        shn[tid]  = hist_nids[b*HL+tid];
        seid[tid] = eidsp[b*HL+tid];
        sts[tid]  = hist_ts[b*HL+tid];
    }
    qns[tid] = qn[b*NF + tid];
    nfn[tid] = node_feat[nids[b]*NF + tid];
    __syncthreads();

    float tlast = sts[HL-1];
    // qh = qn @ attn_wq
    {
        float acc = 0.f;
        for (int d = 0; d < NF; ++d) acc += qns[d]*attn_wq[d*NF + tid];
        qh[tid] = acc;
    }
    __syncthreads();
    // p[d] = sum_j attn_wk[d,j]*qh[j]
    for (int dd = tid; dd < 3*NF; dd += NF) {
        const float4* row4 = (const float4*)(attn_wk + dd*NF);
        float acc = 0.f;
        #pragma unroll
        for (int q4 = 0; q4 < NF/4; ++q4) {
            float4 w4 = row4[q4];
            acc += w4.x*qh[4*q4] + w4.y*qh[4*q4+1] + w4.z*qh[4*q4+2] + w4.w*qh[4*q4+3];
        }
        p[dd] = acc;
    }
    __syncthreads();
    // sc[l] = (p . nb[l]) / sqrt(128), gathering nb[l] straight from global
    int wave = tid >> 6, lane = tid & 63;
    for (int l = wave; l < HL; l += 2) {
        int hn = shn[l], eid = seid[l];
        float dt = tlast - sts[l];
        float acc = 0.f;
        #pragma unroll
        for (int kk = 0; kk < 6; ++kk) {   // d = lane + 64*kk, segments wave-uniform
            int d = lane + 64*kk;
            float v;
            if (d < NF)            v = node_feat[hn*NF + d];
            else if (d < 2*NF)     v = edge_feat[eid*NF + (d-NF)];
            else { int dd = d-2*NF; v = cosf(dt*time_w[dd] + time_b[dd]); }
            acc += p[d]*v;
        }
        for (int off = 32; off > 0; off >>= 1) acc += __shfl_down(acc, off);
        if (lane == 0) {
            bool msk = (hn == 0) && (l != HL-1);
            scl[l] = msk ? -1.0e9f : acc*0.08838834764831845f;  // 1/sqrt(128)
        }
    }
    __syncthreads();
    if (tid == 0) {
        float mx = -3.0e38f;
        for (int m = 0; m < HL; ++m) mx = fmaxf(mx, scl[m]);
        float sum = 0.f;
        for (int m = 0; m < HL; ++m) { float e = expf(scl[m]-mx); al[m] = e; sum += e; }
        float inv = 1.f/sum;
        for (int m = 0; m < HL; ++m) al[m] *= inv;
    }
    __syncthreads();
    // nbar = sum_l a[l]*nb[l]  (second gather pass, L2-warm)
    {
        float twj = time_w[tid], tbj = time_b[tid];
        float an = 0.f, ae = 0.f, at = 0.f;
        #pragma unroll
        for (int l = 0; l < HL; ++l) {
            float a = al[l];
            an += a*node_feat[shn[l]*NF + tid];
            ae += a*edge_feat[seid[l]*NF + tid];
            at += a*cosf((tlast - sts[l])*twj + tbj);
        }
        nbar[tid]       = an;
        nbar[tid+NF]    = ae;
        nbar[tid+2*NF]  = at;
    }
    __syncthreads();
    // ctx2 = nbar @ attn_wv
    {
        float acc = 0.f;
        for (int d = 0; d < 3*NF; ++d) acc += nbar[d]*attn_wv[d*NF + tid];
        ctx2[tid] = acc;
    }
    __syncthreads();
    // h_prev_left
    {
        float acc = merge_b[tid];
        for (int d = 0; d < NF; ++d) acc += ctx2[d]*merge_w[d*NF + tid];
        for (int d = 0; d < NF; ++d) acc += nfn[d]*merge_w[(NF+d)*NF + tid];
        hpl[tid] = tanhf(acc);
    }
    __syncthreads();
    // GRU
    float ghv[3];
    #pragma unroll
    for (int s = 0; s < 3; ++s) {
        int jj = s*NF + tid;
        float acc = gru_b_hh[jj];
        for (int d = 0; d < NF; ++d) acc += hpl[d]*ghT[d*3*NF + jj];
        ghv[s] = acc;
    }
    float gi0 = gi[b*3*NF + tid];
    float gi1 = gi[b*3*NF + NF + tid];
    float gi2 = gi[b*3*NF + 2*NF + tid];
    float r_ = sigmoidf_(gi0 + ghv[0]);
    float z_ = sigmoidf_(gi1 + ghv[1]);
    float n_ = tanhf(gi2 + r_*ghv[2]);
    float hpr = (1.f - z_)*n_ + z_*hpl[tid];
    out[BSZ*NF + b*NF + tid] = hpr;            // h_right
    hpr_out[b*NF + tid] = hpr;                 // for k_ode
    if (tid == 0) out[2*BSZ*NF + b] = tlast;   // hist_ts[:, -1]
}

// ---------------------------------------------------------------------------
// K5: batched RK4 ODE. grid 512, block 256, 8 batches/block (2 blocks/CU,
// everything resident in one pass). Thread = (feature j, batch-quad g);
// ode_w row j in 128 VGPRs; y in LDS as yT[i][8 batches] -> inner loop is
// 1 broadcast float4 read + 4 FMAs per i, 4 independent acc chains.
static __device__ __forceinline__ void ode_eval4(
    const float yin[4], const float4* __restrict__ wr, float obj,
    const float rat[4], float* __restrict__ yT, int j, int g, float kout[4])
{
    float4* yT4 = (float4*)yT;
    __syncthreads();                                 // prior readers done
    yT4[j*2 + g] = make_float4(yin[0], yin[1], yin[2], yin[3]);
    __syncthreads();
    float a0 = obj, a1 = obj, a2 = obj, a3 = obj;
    #pragma unroll
    for (int i = 0; i < NF; i += 4) {
        float4 w  = wr[i>>2];
        float4 yA = yT4[i*2 + g];
        float4 yB = yT4[(i+1)*2 + g];
        float4 yC = yT4[(i+2)*2 + g];
        float4 yD = yT4[(i+3)*2 + g];
        a0 += w.x*yA.x + w.y*yB.x + w.z*yC.x + w.w*yD.x;
        a1 += w.x*yA.y + w.y*yB.y + w.z*yC.y + w.w*yD.y;
        a2 += w.x*yA.z + w.y*yB.z + w.z*yC.z + w.w*yD.z;
        a3 += w.x*yA.w + w.y*yB.w + w.z*yC.w + w.w*yD.w;
    }
    kout[0] = tanhf(a0)*rat[0];
    kout[1] = tanhf(a1)*rat[1];
    kout[2] = tanhf(a2)*rat[2];
    kout[3] = tanhf(a3)*rat[3];
}

__global__ __launch_bounds__(256) void k_ode(
    const float* __restrict__ hpr, const float* __restrict__ hist_ts,
    const float* __restrict__ ode_w, const float* __restrict__ ode_b,
    const float* __restrict__ tnode_w, const float* __restrict__ tnode_b,
    float* __restrict__ out)
{
    __shared__ float yT[NF*8];   // 4 KB, [i][b] layout
    int tid = threadIdx.x;
    int j = tid & (NF-1), g = tid >> 7;
    int b0 = blockIdx.x*8 + g*4;

    float4 wr[32];
    const float4* owr = (const float4*)(ode_w + j*NF);
    #pragma unroll
    for (int i = 0; i < 32; ++i) wr[i] = owr[i];
    float twj = tnode_w[j], tbj = tnode_b[j], obj = ode_b[j];

    float z[4], t0v[4], rat[4];
    #pragma unroll
    for (int q = 0; q < 4; ++q) {
        int b = b0 + q;
        z[q]   = hpr[b*NF + j];
        float t1 = hist_ts[b*HL + (HL-1)];
        t0v[q] = hist_ts[b*HL + (HL-2)];
        rat[q] = t1 - t0v[q];
    }

    float k1[4], k2[4], k3[4], k4[4], yin[4];
    const float dss = 0.125f;
    for (int stp = 0; stp < 8; ++stp) {
        float s0 = stp*dss;
        float teA[4], teB[4], teC[4];
        #pragma unroll
        for (int q = 0; q < 4; ++q) {
            teA[q] = cosf((s0*rat[q] + t0v[q])*twj + tbj);
            teB[q] = cosf(((s0 + 0.0625f)*rat[q] + t0v[q])*twj + tbj);
            teC[q] = cosf(((s0 + 0.125f)*rat[q] + t0v[q])*twj + tbj);
        }
        #pragma unroll
        for (int q = 0; q < 4; ++q) yin[q] = z[q] + teA[q];
        ode_eval4(yin, wr, obj, rat, yT, j, g, k1);
        #pragma unroll
        for (int q = 0; q < 4; ++q) yin[q] = z[q] + 0.0625f*k1[q] + teB[q];
        ode_eval4(yin, wr, obj, rat, yT, j, g, k2);
        #pragma unroll
        for (int q = 0; q < 4; ++q) yin[q] = z[q] + 0.0625f*k2[q] + teB[q];
        ode_eval4(yin, wr, obj, rat, yT, j, g, k3);
        #pragma unroll
        for (int q = 0; q < 4; ++q) yin[q] = z[q] + 0.125f*k3[q] + teC[q];
        ode_eval4(yin, wr, obj, rat, yT, j, g, k4);
        #pragma unroll
        for (int q = 0; q < 4; ++q)
            z[q] += (0.125f/6.f)*(k1[q] + 2.f*k2[q] + 2.f*k3[q] + k4[q]);
    }
    #pragma unroll
    for (int q = 0; q < 4; ++q) out[(b0+q)*NF + j] = z[q];   // h_left
}

// ---------------------------------------------------------------------------
extern "C" void kernel_launch(void* const* d_in, const int* in_sizes, int n_in,
                              void* d_out, int out_size, void* d_ws, size_t ws_size,
                              hipStream_t stream)
{
    (void)in_sizes; (void)n_in; (void)out_size; (void)ws_size;
    const int*   nids      = (const int*)d_in[0];
    const int*   hist_nids = (const int*)d_in[2];
    const int*   aids      = (const int*)d_in[3];
    const int*   eids      = (const int*)d_in[4];
    const float* hist_ts   = (const float*)d_in[5];
    const int*   dirs      = (const int*)d_in[6];
    const float* node_feat = (const float*)d_in[7];
    const float* edge_feat = (const float*)d_in[8];
    const float* anony_emb = (const float*)d_in[9];
    const float* time_w    = (const float*)d_in[10];
    const float* time_b    = (const float*)d_in[11];
    const float* in_proj_w = (const float*)d_in[12];
    const float* in_proj_b = (const float*)d_in[13];
    const float* out_proj_w= (const float*)d_in[14];
    const float* out_proj_b= (const float*)d_in[15];
    const float* outfn_w   = (const float*)d_in[16];
    const float* outfn_b   = (const float*)d_in[17];
    const float* attn_wq   = (const float*)d_in[18];
    const float* attn_wk   = (const float*)d_in[19];
    const float* attn_wv   = (const float*)d_in[20];
    const float* merge_w   = (const float*)d_in[21];
    const float* merge_b   = (const float*)d_in[22];
    const float* gru_w_ih  = (const float*)d_in[23];
    const float* gru_w_hh  = (const float*)d_in[24];
    const float* gru_b_ih  = (const float*)d_in[25];
    const float* gru_b_hh  = (const float*)d_in[26];
    const float* ode_w     = (const float*)d_in[27];
    const float* ode_b     = (const float*)d_in[28];
    const float* tnode_w   = (const float*)d_in[29];
    const float* tnode_b   = (const float*)d_in[30];
    float* out = (float*)d_out;

    float* ws    = (float*)d_ws;
    float* qc    = ws;                   // 640
    float* cc    = ws + 640;             // 2
    float* u     = ws + 768;             // 1280
    float* wbuf  = ws + 2048;            // 4096*1280
    float* lef   = wbuf + BSZ*2*DM;      // 4096*512
    float* qn    = lef + BSZ*DIN;        // 4096*128
    float* gi    = qn + BSZ*NF;          // 4096*384
    float* combT = gi + BSZ*3*NF;        // 640*128
    float* ZZ    = combT + DM*NF;        // 1280*128
    float* qb    = ZZ + 2*DM*NF;         // 128
    float* giT   = qb + NF;              // 512*384
    float* ghT   = giT + DIN*3*NF;       // 128*384
    // hpr aliases wbuf: wbuf's last reader (k_gemm_qn) precedes k_attn2 on
    // the same stream, so reuse is safe and ws footprint stays at ~39.7 MB.
    float* hpr   = wbuf;                 // 4096*128

    // per-launch constant precomputes
    k_comb<<<DM, NF, 0, stream>>>(outfn_w, out_proj_w, combT);
    k_zz<<<2*DM, NF, 0, stream>>>(in_proj_w, combT, ZZ);
    k_qbias<<<1, NF, 0, stream>>>(outfn_b, out_proj_b, outfn_w, in_proj_b, combT, qb);
    k_transpose<<<960, 256, 0, stream>>>(gru_w_ih, gru_w_hh, giT, ghT);
    k_qc<<<5, 128, 0, stream>>>(time_b, in_proj_w, in_proj_b, qc);
    k_cc<<<1, 128, 0, stream>>>(qc, in_proj_b, cc);
    k_u<<<HL, 64, 0, stream>>>(qc, in_proj_w, u);

    // main pipeline
    k_attn1<<<BSZ, 256, 0, stream>>>(nids, hist_nids, aids, eids, hist_ts, dirs,
                                     node_feat, edge_feat, anony_emb,
                                     time_w, time_b, u, cc, wbuf, lef);
    k_gemm_qn<<<BSZ/8, 256, 0, stream>>>(wbuf, ZZ, qb, qn);
    k_gemm_gi<<<BSZ/8, 256, 0, stream>>>(lef, giT, gru_b_ih, gi);
    k_attn2<<<BSZ, 128, 0, stream>>>(nids, hist_nids, eids, hist_ts,
                                     node_feat, edge_feat, time_w, time_b,
                                     attn_wq, attn_wk, attn_wv, merge_w, merge_b,
                                     qn, gi, ghT, gru_b_hh, hpr, out);
    k_ode<<<BSZ/8, 256, 0, stream>>>(hpr, hist_ts, ode_w, ode_b,
                                     tnode_w, tnode_b, out);
}

// Round 3
// 1360.598 us; speedup vs baseline: 2.9728x; 2.9728x over previous
//
#include <hip/hip_runtime.h>
#include <math.h>

// Problem constants (from reference)
#define BSZ 4096
#define HL  20
#define NF  128
#define DM  640      // 3*NF + EF + TF
#define DIN 512      // DM - TF
#define DH  320      // DM / NHEAD

static __device__ __forceinline__ float sigmoidf_(float x){ return 1.f/(1.f+expf(-x)); }

// ---------------------------------------------------------------------------
// T1: combT[jc*128+jq] = (outfn_w @ out_proj_w)[jq, jc]
// grid 640, block 128
__global__ void k_comb(const float* __restrict__ outfn_w,
                       const float* __restrict__ out_proj_w,
                       float* __restrict__ combT)
{
    int jc = blockIdx.x, jq = threadIdx.x;
    float acc = 0.f;
    for (int e = 0; e < DM; ++e)
        acc += outfn_w[jq*DM + e] * out_proj_w[e*DM + jc];
    combT[jc*NF + jq] = acc;
}

// T2: ZZ[ef*128+jq]
// grid 1280, block 128
__global__ void k_zz(const float* __restrict__ in_proj_w,
                     const float* __restrict__ combT,
                     float* __restrict__ ZZ)
{
    int ef = blockIdx.x;
    int h = ef / DM, e = ef - h*DM;
    int jq = threadIdx.x;
    const float* wv = in_proj_w + (2*DM + h*DH)*DM + e;   // + dd*DM
    const float* cb = combT + (h*DH)*NF + jq;             // + dd*NF
    float acc = 0.f;
    for (int dd = 0; dd < DH; ++dd)
        acc += wv[dd*DM] * cb[dd*NF];
    ZZ[ef*NF + jq] = acc;
}

// T3: qbias
// grid 1, block 128
__global__ void k_qbias(const float* __restrict__ outfn_b,
                        const float* __restrict__ out_proj_b,
                        const float* __restrict__ outfn_w,
                        const float* __restrict__ in_proj_b,
                        const float* __restrict__ combT,
                        float* __restrict__ qb)
{
    int jq = threadIdx.x;
    float acc = outfn_b[jq];
    for (int e = 0; e < DM; ++e)  acc += out_proj_b[e] * outfn_w[jq*DM + e];
    for (int jc = 0; jc < DM; ++jc) acc += in_proj_b[2*DM + jc] * combT[jc*NF + jq];
    qb[jq] = acc;
}

// T4: transposes
// grid 960, block 256
__global__ void k_transpose(const float* __restrict__ gih,
                            const float* __restrict__ ghh,
                            float* __restrict__ giT,
                            float* __restrict__ ghT)
{
    int i = blockIdx.x*blockDim.x + threadIdx.x;
    if (i < DIN*3*NF) {
        int d = i / (3*NF), j = i - d*(3*NF);
        giT[i] = gih[j*DIN + d];
    } else {
        int i2 = i - DIN*3*NF;
        int d = i2 / (3*NF), j = i2 - d*(3*NF);
        ghT[i2] = ghh[j*NF + d];
    }
}

// K2a: qc[j]
// grid 5, block 128
__global__ void k_qc(const float* __restrict__ time_b,
                     const float* __restrict__ in_proj_w,
                     const float* __restrict__ in_proj_b,
                     float* __restrict__ qcv)
{
    __shared__ float tsr[NF];
    int tid = threadIdx.x;
    tsr[tid] = cosf(time_b[tid]);
    __syncthreads();
    int j = blockIdx.x*128 + tid;
    const float* wr = in_proj_w + j*DM + DIN;
    float acc = in_proj_b[j];
    for (int d = 0; d < NF; ++d) acc += tsr[d]*wr[d];
    qcv[j] = acc;
}

// K2a2: cc[h]
// grid 1, block 128
__global__ void k_cc(const float* __restrict__ qcv,
                     const float* __restrict__ in_proj_b,
                     float* __restrict__ cc)
{
    int wave = threadIdx.x >> 6, lane = threadIdx.x & 63;
    float acc = 0.f;
    for (int j = lane; j < DH; j += 64)
        acc += qcv[wave*DH + j] * in_proj_b[DM + wave*DH + j];
    for (int off = 32; off > 0; off >>= 1) acc += __shfl_down(acc, off);
    if (lane == 0) cc[wave] = acc;
}

// K2b: u
// grid 20, block 64
__global__ void k_u(const float* __restrict__ qcv,
                    const float* __restrict__ in_proj_w,
                    float* __restrict__ u)
{
    int d = blockIdx.x*64 + threadIdx.x;
    int h = d / DM, dd = d - h*DM;
    const float* base = in_proj_w + (DM + h*DH)*DM + dd;
    const float* q = qcv + h*DH;
    float acc = 0.f;
    for (int j = 0; j < DH; ++j) acc += q[j]*base[j*DM];
    u[d] = acc;
}

// ---------------------------------------------------------------------------
// K3: per-batch fused build + MHA attention (collapsed form).
// grid 4096, block 256
__global__ __launch_bounds__(256) void k_attn1(
    const int* __restrict__ nids, const int* __restrict__ hist_nids,
    const int* __restrict__ aidsp, const int* __restrict__ eidsp,
    const float* __restrict__ hist_ts, const int* __restrict__ dirsp,
    const float* __restrict__ node_feat, const float* __restrict__ edge_feat,
    const float* __restrict__ anony_emb,
    const float* __restrict__ time_w, const float* __restrict__ time_b,
    const float* __restrict__ u, const float* __restrict__ cc,
    float* __restrict__ wbuf, float* __restrict__ lef)
{
    int b = blockIdx.x, tid = threadIdx.x;
    __shared__ float zf[HL][DM];      // 51.2 KB
    __shared__ float ul[2*DM];
    __shared__ float sc[2][HL];
    __shared__ float aw[2][HL];
    __shared__ int   shn[HL], sdir[HL], said[HL], seid[HL];
    __shared__ float sts[HL];

    if (tid < HL) {
        shn[tid]  = hist_nids[b*HL+tid];
        sdir[tid] = dirsp[b*HL+tid];
        said[tid] = aidsp[b*HL+tid];
        seid[tid] = eidsp[b*HL+tid];
        sts[tid]  = hist_ts[b*HL+tid];
    }
    for (int i = tid; i < 2*DM; i += 256) ul[i] = u[i];
    __syncthreads();

    int rnid = nids[b];
    float tlast = sts[HL-1];
    for (int l = 0; l < HL; ++l) {
        int hn = shn[l], dir = sdir[l];
        int srcn = dir ? rnid : hn;
        int dstn = dir ? hn : rnid;
        int aid = said[l], eid = seid[l];
        float dt = tlast - sts[l];
        for (int c = tid; c < DM; c += 256) {
            float v;
            if (c < NF)            v = node_feat[srcn*NF + c];
            else if (c < 2*NF)     v = node_feat[dstn*NF + (c-NF)];
            else if (c < 3*NF)     v = anony_emb[aid*NF + (c-2*NF)];
            else if (c < 4*NF)     v = edge_feat[eid*NF + (c-3*NF)];
            else { int d = c - 4*NF; v = cosf(dt*time_w[d] + time_b[d]); }
            if (l == HL-1 && c < DIN) { lef[b*DIN + c] = v; v = 0.f; }
            zf[l][c] = v;
        }
    }
    __syncthreads();

    int wave = tid >> 6, lane = tid & 63;
    float c0 = cc[0], c1 = cc[1];
    for (int pr = wave; pr < 2*HL; pr += 4) {
        int h = pr / HL, m = pr - h*HL;
        float acc = 0.f;
        for (int d = lane; d < DM; d += 64) acc += ul[h*DM + d]*zf[m][d];
        for (int off = 32; off > 0; off >>= 1) acc += __shfl_down(acc, off);
        if (lane == 0) {
            float s = (acc + (h ? c1 : c0)) * 0.05590169943749474f; // 1/sqrt(320)
            bool msk = (shn[m] == 0) && (m != HL-1);
            sc[h][m] = msk ? -1.0e9f : s;
        }
    }
    __syncthreads();
    if (tid < 2) {
        float mx = -3.0e38f;
        for (int m = 0; m < HL; ++m) mx = fmaxf(mx, sc[tid][m]);
        float sum = 0.f;
        for (int m = 0; m < HL; ++m) { float e = expf(sc[tid][m]-mx); aw[tid][m] = e; sum += e; }
        float inv = 1.f/sum;
        for (int m = 0; m < HL; ++m) aw[tid][m] *= inv;
    }
    __syncthreads();
    for (int i = tid; i < 2*DM; i += 256) {
        int h = i / DM, d = i - h*DM;
        float acc = 0.f;
        #pragma unroll
        for (int m = 0; m < HL; ++m) acc += aw[h][m]*zf[m][d];
        wbuf[b*2*DM + i] = acc;
    }
}

// ---------------------------------------------------------------------------
// Row-block GEMM: qn = wbuf @ ZZ + qbias
__global__ __launch_bounds__(256) void k_gemm_qn(const float* __restrict__ A,
                                                 const float* __restrict__ BT,
                                                 const float* __restrict__ bias,
                                                 float* __restrict__ C)
{
    constexpr int K = 2*DM;  // 1280
    __shared__ float As[8*K];   // 40 KB
    int r0 = blockIdx.x*8, tid = threadIdx.x;
    for (int i = tid; i < 8*K; i += 256) As[i] = A[r0*K + i];
    __syncthreads();
    int j = tid & (NF-1), rh = tid >> 7;
    const float* bp = BT + j;
    const float* ap = As + rh*4*K;
    float acc0=0.f, acc1=0.f, acc2=0.f, acc3=0.f;
    for (int d = 0; d < K; ++d) {
        float bv = bp[d*NF];
        acc0 += ap[d]*bv;
        acc1 += ap[K + d]*bv;
        acc2 += ap[2*K + d]*bv;
        acc3 += ap[3*K + d]*bv;
    }
    float bsv = bias[j];
    int rb = r0 + rh*4;
    C[(rb+0)*NF + j] = acc0 + bsv;
    C[(rb+1)*NF + j] = acc1 + bsv;
    C[(rb+2)*NF + j] = acc2 + bsv;
    C[(rb+3)*NF + j] = acc3 + bsv;
}

// Row-block GEMM: gi = lef @ giT + gru_b_ih
__global__ __launch_bounds__(256) void k_gemm_gi(const float* __restrict__ A,
                                                 const float* __restrict__ BT,
                                                 const float* __restrict__ bias,
                                                 float* __restrict__ C)
{
    constexpr int K = DIN;     // 512
    constexpr int N = 3*NF;    // 384
    __shared__ float As[8*K];  // 16 KB
    int r0 = blockIdx.x*8, tid = threadIdx.x;
    for (int i = tid; i < 8*K; i += 256) As[i] = A[r0*K + i];
    __syncthreads();
    int j0 = tid, j1 = tid + 256;
    bool has1 = (j1 < N);
    float a0[8] = {0,0,0,0,0,0,0,0};
    float a1[8] = {0,0,0,0,0,0,0,0};
    for (int d = 0; d < K; ++d) {
        float b0 = BT[d*N + j0];
        float b1 = 0.f;
        if (has1) b1 = BT[d*N + j1];
        #pragma unroll
        for (int r = 0; r < 8; ++r) {
            float av = As[r*K + d];
            a0[r] += av*b0;
            a1[r] += av*b1;
        }
    }
    float bs0 = bias[j0];
    for (int r = 0; r < 8; ++r) C[(r0+r)*N + j0] = a0[r] + bs0;
    if (has1) {
        float bs1 = bias[j1];
        for (int r = 0; r < 8; ++r) C[(r0+r)*N + j1] = a1[r] + bs1;
    }
}

// ---------------------------------------------------------------------------
// K4: attention2 (collapsed) + merge + GRU.  grid 4096, block 128.
__global__ __launch_bounds__(128) void k_attn2(
    const int* __restrict__ nids, const int* __restrict__ hist_nids,
    const int* __restrict__ eidsp, const float* __restrict__ hist_ts,
    const float* __restrict__ node_feat, const float* __restrict__ edge_feat,
    const float* __restrict__ time_w, const float* __restrict__ time_b,
    const float* __restrict__ attn_wq, const float* __restrict__ attn_wk,
    const float* __restrict__ attn_wv,
    const float* __restrict__ merge_w, const float* __restrict__ merge_b,
    const float* __restrict__ qn, const float* __restrict__ gi,
    const float* __restrict__ ghT, const float* __restrict__ gru_b_hh,
    float* __restrict__ hpr_out, float* __restrict__ out)
{
    int b = blockIdx.x, tid = threadIdx.x;
    __shared__ float qns[NF], qh[NF], p[3*NF], nbar[3*NF];
    __shared__ float scl[HL], al[HL];
    __shared__ float ctx2[NF], hpl[NF], nfn[NF];
    __shared__ int   shn[HL], seid[HL];
    __shared__ float sts[HL];

    if (tid < HL) {
        shn[tid]  = hist_nids[b*HL+tid];
        seid[tid] = eidsp[b*HL+tid];
        sts[tid]  = hist_ts[b*HL+tid];
    }
    qns[tid] = qn[b*NF + tid];
    nfn[tid] = node_feat[nids[b]*NF + tid];
    __syncthreads();

    float tlast = sts[HL-1];
    // qh = qn @ attn_wq
    {
        float acc = 0.f;
        for (int d = 0; d < NF; ++d) acc += qns[d]*attn_wq[d*NF + tid];
        qh[tid] = acc;
    }
    __syncthreads();
    // p[d] = sum_j attn_wk[d,j]*qh[j]
    for (int dd = tid; dd < 3*NF; dd += NF) {
        const float4* row4 = (const float4*)(attn_wk + dd*NF);
        float acc = 0.f;
        #pragma unroll
        for (int q4 = 0; q4 < NF/4; ++q4) {
            float4 w4 = row4[q4];
            acc += w4.x*qh[4*q4] + w4.y*qh[4*q4+1] + w4.z*qh[4*q4+2] + w4.w*qh[4*q4+3];
        }
        p[dd] = acc;
    }
    __syncthreads();
    // sc[l] = (p . nb[l]) / sqrt(128), gathering nb[l] straight from global
    int wave = tid >> 6, lane = tid & 63;
    for (int l = wave; l < HL; l += 2) {
        int hn = shn[l], eid = seid[l];
        float dt = tlast - sts[l];
        float acc = 0.f;
        #pragma unroll
        for (int kk = 0; kk < 6; ++kk) {
            int d = lane + 64*kk;
            float v;
            if (d < NF)            v = node_feat[hn*NF + d];
            else if (d < 2*NF)     v = edge_feat[eid*NF + (d-NF)];
            else { int dd = d-2*NF; v = cosf(dt*time_w[dd] + time_b[dd]); }
            acc += p[d]*v;
        }
        for (int off = 32; off > 0; off >>= 1) acc += __shfl_down(acc, off);
        if (lane == 0) {
            bool msk = (hn == 0) && (l != HL-1);
            scl[l] = msk ? -1.0e9f : acc*0.08838834764831845f;  // 1/sqrt(128)
        }
    }
    __syncthreads();
    if (tid == 0) {
        float mx = -3.0e38f;
        for (int m = 0; m < HL; ++m) mx = fmaxf(mx, scl[m]);
        float sum = 0.f;
        for (int m = 0; m < HL; ++m) { float e = expf(scl[m]-mx); al[m] = e; sum += e; }
        float inv = 1.f/sum;
        for (int m = 0; m < HL; ++m) al[m] *= inv;
    }
    __syncthreads();
    // nbar = sum_l a[l]*nb[l]  (second gather pass, L2-warm)
    {
        float twj = time_w[tid], tbj = time_b[tid];
        float an = 0.f, ae = 0.f, at = 0.f;
        #pragma unroll
        for (int l = 0; l < HL; ++l) {
            float a = al[l];
            an += a*node_feat[shn[l]*NF + tid];
            ae += a*edge_feat[seid[l]*NF + tid];
            at += a*cosf((tlast - sts[l])*twj + tbj);
        }
        nbar[tid]       = an;
        nbar[tid+NF]    = ae;
        nbar[tid+2*NF]  = at;
    }
    __syncthreads();
    // ctx2 = nbar @ attn_wv
    {
        float acc = 0.f;
        for (int d = 0; d < 3*NF; ++d) acc += nbar[d]*attn_wv[d*NF + tid];
        ctx2[tid] = acc;
    }
    __syncthreads();
    // h_prev_left
    {
        float acc = merge_b[tid];
        for (int d = 0; d < NF; ++d) acc += ctx2[d]*merge_w[d*NF + tid];
        for (int d = 0; d < NF; ++d) acc += nfn[d]*merge_w[(NF+d)*NF + tid];
        hpl[tid] = tanhf(acc);
    }
    __syncthreads();
    // GRU
    float ghv[3];
    #pragma unroll
    for (int s = 0; s < 3; ++s) {
        int jj = s*NF + tid;
        float acc = gru_b_hh[jj];
        for (int d = 0; d < NF; ++d) acc += hpl[d]*ghT[d*3*NF + jj];
        ghv[s] = acc;
    }
    float gi0 = gi[b*3*NF + tid];
    float gi1 = gi[b*3*NF + NF + tid];
    float gi2 = gi[b*3*NF + 2*NF + tid];
    float r_ = sigmoidf_(gi0 + ghv[0]);
    float z_ = sigmoidf_(gi1 + ghv[1]);
    float n_ = tanhf(gi2 + r_*ghv[2]);
    float hpr = (1.f - z_)*n_ + z_*hpl[tid];
    out[BSZ*NF + b*NF + tid] = hpr;            // h_right
    hpr_out[b*NF + tid] = hpr;                 // for k_ode
    if (tid == 0) out[2*BSZ*NF + b] = tlast;   // hist_ts[:, -1]
}

// ---------------------------------------------------------------------------
// K5: batched RK4 ODE, Q=2 batches/thread (no spill: 128 w-VGPRs + ~40 state).
// Block 256 = 2 feature-groups x 128 j; 4 batches/block; grid 1024.
// y exchange via 2KB LDS laid out per-batch contiguous: writes lane-consecutive
// b32 (conflict-free), reads wave-uniform float4 broadcasts (g uniform per wave).
static __device__ __forceinline__ void ode_eval2(
    const float yin0, const float yin1, const float4* __restrict__ wr, float obj,
    const float rat0, const float rat1, float* __restrict__ yb, int j, int g,
    float* k0, float* k1)
{
    __syncthreads();                      // prior readers of yb done
    yb[(2*g+0)*NF + j] = yin0;
    yb[(2*g+1)*NF + j] = yin1;
    __syncthreads();
    const float4* yA4 = (const float4*)(yb + (2*g+0)*NF);
    const float4* yB4 = (const float4*)(yb + (2*g+1)*NF);
    float a0 = obj, a1 = obj, b0 = 0.f, b1 = 0.f;  // 2 acc chains per batch (ILP)
    #pragma unroll
    for (int q = 0; q < 32; q += 2) {
        float4 w0 = wr[q],   w1 = wr[q+1];
        float4 ya0 = yA4[q], yc0 = yB4[q];
        float4 ya1 = yA4[q+1], yc1 = yB4[q+1];
        a0 += w0.x*ya0.x + w0.y*ya0.y + w0.z*ya0.z + w0.w*ya0.w;
        a1 += w0.x*yc0.x + w0.y*yc0.y + w0.z*yc0.z + w0.w*yc0.w;
        b0 += w1.x*ya1.x + w1.y*ya1.y + w1.z*ya1.z + w1.w*ya1.w;
        b1 += w1.x*yc1.x + w1.y*yc1.y + w1.z*yc1.z + w1.w*yc1.w;
    }
    *k0 = tanhf(a0 + b0)*rat0;
    *k1 = tanhf(a1 + b1)*rat1;
}

__global__ __launch_bounds__(256) void k_ode(
    const float* __restrict__ hpr, const float* __restrict__ hist_ts,
    const float* __restrict__ ode_w, const float* __restrict__ ode_b,
    const float* __restrict__ tnode_w, const float* __restrict__ tnode_b,
    float* __restrict__ out)
{
    __shared__ float yb[4*NF];   // 2 KB, per-batch contiguous rows
    int tid = threadIdx.x;
    int j = tid & (NF-1), g = tid >> 7;     // g in {0,1}, uniform per wave
    int b0 = blockIdx.x*4 + g*2;

    float4 wr[32];
    const float4* owr = (const float4*)(ode_w + j*NF);
    #pragma unroll
    for (int i = 0; i < 32; ++i) wr[i] = owr[i];
    float twj = tnode_w[j], tbj = tnode_b[j], obj = ode_b[j];

    float z0, z1, t00, t01, rat0, rat1;
    {
        float t1a = hist_ts[(b0+0)*HL + (HL-1)];
        float t1b = hist_ts[(b0+1)*HL + (HL-1)];
        t00 = hist_ts[(b0+0)*HL + (HL-2)];
        t01 = hist_ts[(b0+1)*HL + (HL-2)];
        rat0 = t1a - t00; rat1 = t1b - t01;
        z0 = hpr[(b0+0)*NF + j];
        z1 = hpr[(b0+1)*NF + j];
    }

    const float dss = 0.125f;
    #pragma unroll 1
    for (int stp = 0; stp < 8; ++stp) {
        float s0 = stp*dss;
        float teA0 = cosf((s0*rat0 + t00)*twj + tbj);
        float teA1 = cosf((s0*rat1 + t01)*twj + tbj);
        float teB0 = cosf(((s0 + 0.0625f)*rat0 + t00)*twj + tbj);
        float teB1 = cosf(((s0 + 0.0625f)*rat1 + t01)*twj + tbj);
        float teC0 = cosf(((s0 + 0.125f)*rat0 + t00)*twj + tbj);
        float teC1 = cosf(((s0 + 0.125f)*rat1 + t01)*twj + tbj);
        float k10, k11, k20, k21, k30, k31, k40, k41;
        ode_eval2(z0 + teA0,               z1 + teA1,               wr, obj, rat0, rat1, yb, j, g, &k10, &k11);
        ode_eval2(z0 + 0.0625f*k10 + teB0, z1 + 0.0625f*k11 + teB1, wr, obj, rat0, rat1, yb, j, g, &k20, &k21);
        ode_eval2(z0 + 0.0625f*k20 + teB0, z1 + 0.0625f*k21 + teB1, wr, obj, rat0, rat1, yb, j, g, &k30, &k31);
        ode_eval2(z0 + 0.125f*k30 + teC0,  z1 + 0.125f*k31 + teC1,  wr, obj, rat0, rat1, yb, j, g, &k40, &k41);
        z0 += (0.125f/6.f)*(k10 + 2.f*k20 + 2.f*k30 + k40);
        z1 += (0.125f/6.f)*(k11 + 2.f*k21 + 2.f*k31 + k41);
    }
    out[(b0+0)*NF + j] = z0;   // h_left
    out[(b0+1)*NF + j] = z1;
}

// ---------------------------------------------------------------------------
extern "C" void kernel_launch(void* const* d_in, const int* in_sizes, int n_in,
                              void* d_out, int out_size, void* d_ws, size_t ws_size,
                              hipStream_t stream)
{
    (void)in_sizes; (void)n_in; (void)out_size; (void)ws_size;
    const int*   nids      = (const int*)d_in[0];
    const int*   hist_nids = (const int*)d_in[2];
    const int*   aids      = (const int*)d_in[3];
    const int*   eids      = (const int*)d_in[4];
    const float* hist_ts   = (const float*)d_in[5];
    const int*   dirs      = (const int*)d_in[6];
    const float* node_feat = (const float*)d_in[7];
    const float* edge_feat = (const float*)d_in[8];
    const float* anony_emb = (const float*)d_in[9];
    const float* time_w    = (const float*)d_in[10];
    const float* time_b    = (const float*)d_in[11];
    const float* in_proj_w = (const float*)d_in[12];
    const float* in_proj_b = (const float*)d_in[13];
    const float* out_proj_w= (const float*)d_in[14];
    const float* out_proj_b= (const float*)d_in[15];
    const float* outfn_w   = (const float*)d_in[16];
    const float* outfn_b   = (const float*)d_in[17];
    const float* attn_wq   = (const float*)d_in[18];
    const float* attn_wk   = (const float*)d_in[19];
    const float* attn_wv   = (const float*)d_in[20];
    const float* merge_w   = (const float*)d_in[21];
    const float* merge_b   = (const float*)d_in[22];
    const float* gru_w_ih  = (const float*)d_in[23];
    const float* gru_w_hh  = (const float*)d_in[24];
    const float* gru_b_ih  = (const float*)d_in[25];
    const float* gru_b_hh  = (const float*)d_in[26];
    const float* ode_w     = (const float*)d_in[27];
    const float* ode_b     = (const float*)d_in[28];
    const float* tnode_w   = (const float*)d_in[29];
    const float* tnode_b   = (const float*)d_in[30];
    float* out = (float*)d_out;

    float* ws    = (float*)d_ws;
    float* qc    = ws;                   // 640
    float* cc    = ws + 640;             // 2
    float* u     = ws + 768;             // 1280
    float* wbuf  = ws + 2048;            // 4096*1280
    float* lef   = wbuf + BSZ*2*DM;      // 4096*512
    float* qn    = lef + BSZ*DIN;        // 4096*128
    float* gi    = qn + BSZ*NF;          // 4096*384
    float* combT = gi + BSZ*3*NF;        // 640*128
    float* ZZ    = combT + DM*NF;        // 1280*128
    float* qb    = ZZ + 2*DM*NF;         // 128
    float* giT   = qb + NF;              // 512*384
    float* ghT   = giT + DIN*3*NF;       // 128*384
    // hpr aliases wbuf: wbuf's last reader (k_gemm_qn) precedes k_attn2 on
    // the same stream, so reuse is safe.
    float* hpr   = wbuf;                 // 4096*128

    // per-launch constant precomputes
    k_comb<<<DM, NF, 0, stream>>>(outfn_w, out_proj_w, combT);
    k_zz<<<2*DM, NF, 0, stream>>>(in_proj_w, combT, ZZ);
    k_qbias<<<1, NF, 0, stream>>>(outfn_b, out_proj_b, outfn_w, in_proj_b, combT, qb);
    k_transpose<<<960, 256, 0, stream>>>(gru_w_ih, gru_w_hh, giT, ghT);
    k_qc<<<5, 128, 0, stream>>>(time_b, in_proj_w, in_proj_b, qc);
    k_cc<<<1, 128, 0, stream>>>(qc, in_proj_b, cc);
    k_u<<<HL, 64, 0, stream>>>(qc, in_proj_w, u);

    // main pipeline
    k_attn1<<<BSZ, 256, 0, stream>>>(nids, hist_nids, aids, eids, hist_ts, dirs,
                                     node_feat, edge_feat, anony_emb,
                                     time_w, time_b, u, cc, wbuf, lef);
    k_gemm_qn<<<BSZ/8, 256, 0, stream>>>(wbuf, ZZ, qb, qn);
    k_gemm_gi<<<BSZ/8, 256, 0, stream>>>(lef, giT, gru_b_ih, gi);
    k_attn2<<<BSZ, 128, 0, stream>>>(nids, hist_nids, eids, hist_ts,
                                     node_feat, edge_feat, time_w, time_b,
                                     attn_wq, attn_wk, attn_wv, merge_w, merge_b,
                                     qn, gi, ghT, gru_b_hh, hpr, out);
    k_ode<<<BSZ/4, 256, 0, stream>>>(hpr, hist_ts, ode_w, ode_b,
                                     tnode_w, tnode_b, out);
}

// Round 4
// 1125.471 us; speedup vs baseline: 3.5938x; 1.2089x over previous
//
#include <hip/hip_runtime.h>
#include <math.h>

// Problem constants (from reference)
#define BSZ 4096
#define HL  20
#define NF  128
#define DM  640      // 3*NF + EF + TF
#define DIN 512      // DM - TF
#define DH  320      // DM / NHEAD

static __device__ __forceinline__ float sigmoidf_(float x){ return 1.f/(1.f+expf(-x)); }
// bf16 truncate-with-round staging helpers (LDS footprint halving)
static __device__ __forceinline__ unsigned short f2b_(float v){
    return (unsigned short)((__float_as_uint(v) + 0x8000u) >> 16);
}
static __device__ __forceinline__ float b2f_(unsigned short u){
    return __uint_as_float(((unsigned int)u) << 16);
}

// ---------------------------------------------------------------------------
// T1: combT[jc*128+jq] = (outfn_w @ out_proj_w)[jq, jc]
// grid 640, block 128
__global__ void k_comb(const float* __restrict__ outfn_w,
                       const float* __restrict__ out_proj_w,
                       float* __restrict__ combT)
{
    int jc = blockIdx.x, jq = threadIdx.x;
    float acc = 0.f;
    for (int e = 0; e < DM; ++e)
        acc += outfn_w[jq*DM + e] * out_proj_w[e*DM + jc];
    combT[jc*NF + jq] = acc;
}

// T2: ZZ[ef*128+jq]
// grid 1280, block 128
__global__ void k_zz(const float* __restrict__ in_proj_w,
                     const float* __restrict__ combT,
                     float* __restrict__ ZZ)
{
    int ef = blockIdx.x;
    int h = ef / DM, e = ef - h*DM;
    int jq = threadIdx.x;
    const float* wv = in_proj_w + (2*DM + h*DH)*DM + e;   // + dd*DM
    const float* cb = combT + (h*DH)*NF + jq;             // + dd*NF
    float acc = 0.f;
    for (int dd = 0; dd < DH; ++dd)
        acc += wv[dd*DM] * cb[dd*NF];
    ZZ[ef*NF + jq] = acc;
}

// T3: qbias
// grid 1, block 128
__global__ void k_qbias(const float* __restrict__ outfn_b,
                        const float* __restrict__ out_proj_b,
                        const float* __restrict__ outfn_w,
                        const float* __restrict__ in_proj_b,
                        const float* __restrict__ combT,
                        float* __restrict__ qb)
{
    int jq = threadIdx.x;
    float acc = outfn_b[jq];
    for (int e = 0; e < DM; ++e)  acc += out_proj_b[e] * outfn_w[jq*DM + e];
    for (int jc = 0; jc < DM; ++jc) acc += in_proj_b[2*DM + jc] * combT[jc*NF + jq];
    qb[jq] = acc;
}

// T4: transposes
// grid 960, block 256
__global__ void k_transpose(const float* __restrict__ gih,
                            const float* __restrict__ ghh,
                            float* __restrict__ giT,
                            float* __restrict__ ghT)
{
    int i = blockIdx.x*blockDim.x + threadIdx.x;
    if (i < DIN*3*NF) {
        int d = i / (3*NF), j = i - d*(3*NF);
        giT[i] = gih[j*DIN + d];
    } else {
        int i2 = i - DIN*3*NF;
        int d = i2 / (3*NF), j = i2 - d*(3*NF);
        ghT[i2] = ghh[j*NF + d];
    }
}

// K2a: qc[j]
// grid 5, block 128
__global__ void k_qc(const float* __restrict__ time_b,
                     const float* __restrict__ in_proj_w,
                     const float* __restrict__ in_proj_b,
                     float* __restrict__ qcv)
{
    __shared__ float tsr[NF];
    int tid = threadIdx.x;
    tsr[tid] = cosf(time_b[tid]);
    __syncthreads();
    int j = blockIdx.x*128 + tid;
    const float* wr = in_proj_w + j*DM + DIN;
    float acc = in_proj_b[j];
    for (int d = 0; d < NF; ++d) acc += tsr[d]*wr[d];
    qcv[j] = acc;
}

// K2a2: cc[h]
// grid 1, block 128
__global__ void k_cc(const float* __restrict__ qcv,
                     const float* __restrict__ in_proj_b,
                     float* __restrict__ cc)
{
    int wave = threadIdx.x >> 6, lane = threadIdx.x & 63;
    float acc = 0.f;
    for (int j = lane; j < DH; j += 64)
        acc += qcv[wave*DH + j] * in_proj_b[DM + wave*DH + j];
    for (int off = 32; off > 0; off >>= 1) acc += __shfl_down(acc, off);
    if (lane == 0) cc[wave] = acc;
}

// K2b: u
// grid 20, block 64
__global__ void k_u(const float* __restrict__ qcv,
                    const float* __restrict__ in_proj_w,
                    float* __restrict__ u)
{
    int d = blockIdx.x*64 + threadIdx.x;
    int h = d / DM, dd = d - h*DM;
    const float* base = in_proj_w + (DM + h*DH)*DM + dd;
    const float* q = qcv + h*DH;
    float acc = 0.f;
    for (int j = 0; j < DH; ++j) acc += q[j]*base[j*DM];
    u[d] = acc;
}

// ---------------------------------------------------------------------------
// K3: per-batch fused build + MHA attention (collapsed form), restructured:
// wave-per-row register gathering (40 outstanding loads/wave), score dot fused
// into the gather, bf16 LDS staging for the attention-weighted sum.
// grid 4096, block 256 (4 waves, 5 rows each)
__global__ __launch_bounds__(256) void k_attn1(
    const int* __restrict__ nids, const int* __restrict__ hist_nids,
    const int* __restrict__ aidsp, const int* __restrict__ eidsp,
    const float* __restrict__ hist_ts, const int* __restrict__ dirsp,
    const float* __restrict__ node_feat, const float* __restrict__ edge_feat,
    const float* __restrict__ anony_emb,
    const float* __restrict__ time_w, const float* __restrict__ time_b,
    const float* __restrict__ u, const float* __restrict__ cc,
    float* __restrict__ wbuf, float* __restrict__ lef)
{
    int b = blockIdx.x, tid = threadIdx.x;
    int wave = tid >> 6, lane = tid & 63;
    __shared__ unsigned short zh[HL][DM];   // 25.6 KB (bf16)
    __shared__ float ul[2*DM];              // 5 KB
    __shared__ float sc[2][HL];
    __shared__ float aw[2][HL];
    __shared__ int   shn[HL], sdir[HL], said[HL], seid[HL];
    __shared__ float sts[HL];

    if (tid < HL) {
        shn[tid]  = hist_nids[b*HL+tid];
        sdir[tid] = dirsp[b*HL+tid];
        said[tid] = aidsp[b*HL+tid];
        seid[tid] = eidsp[b*HL+tid];
        sts[tid]  = hist_ts[b*HL+tid];
    }
    for (int i = tid; i < 2*DM; i += 256) ul[i] = u[i];
    float twA = time_w[lane],    tbA = time_b[lane];
    float twB = time_w[64+lane], tbB = time_b[64+lane];
    __syncthreads();

    // preload u fragments for the fused score dot: c = lane + 64*s
    float ulr0[10], ulr1[10];
    #pragma unroll
    for (int s = 0; s < 10; ++s) {
        ulr0[s] = ul[s*64 + lane];
        ulr1[s] = ul[DM + s*64 + lane];
    }

    int rnid = nids[b];
    float tlast = sts[HL-1];

    // per-row indices (rows l = wave + 4*r)
    int srcv[5], dstv[5], aidv[5], eidv[5];
    float dtv[5];
    #pragma unroll
    for (int r = 0; r < 5; ++r) {
        int l = wave + 4*r;
        int hn = shn[l], dir = sdir[l];
        srcv[r] = dir ? rnid : hn;
        dstv[r] = dir ? hn : rnid;
        aidv[r] = said[l];
        eidv[r] = eidv[r] = seid[l];
        dtv[r]  = tlast - sts[l];
    }
    // issue all gathers (independent -> stay in flight together)
    float zr[5][10];
    #pragma unroll
    for (int r = 0; r < 5; ++r) {
        zr[r][0] = node_feat[srcv[r]*NF + lane];
        zr[r][1] = node_feat[srcv[r]*NF + 64 + lane];
        zr[r][2] = node_feat[dstv[r]*NF + lane];
        zr[r][3] = node_feat[dstv[r]*NF + 64 + lane];
        zr[r][4] = anony_emb[aidv[r]*NF + lane];
        zr[r][5] = anony_emb[aidv[r]*NF + 64 + lane];
        zr[r][6] = edge_feat[eidv[r]*NF + lane];
        zr[r][7] = edge_feat[eidv[r]*NF + 64 + lane];
        zr[r][8] = cosf(dtv[r]*twA + tbA);
        zr[r][9] = cosf(dtv[r]*twB + tbB);
    }
    float c0 = cc[0], c1 = cc[1];
    // process rows: lef write / zeroing, fused score dot, bf16 LDS store
    #pragma unroll
    for (int r = 0; r < 5; ++r) {
        int l = wave + 4*r;
        if (l == HL-1) {            // wave-uniform (wave 3, r 4 only)
            #pragma unroll
            for (int s = 0; s < 8; ++s) {
                lef[b*DIN + s*64 + lane] = zr[r][s];
                zr[r][s] = 0.f;
            }
        }
        float d0 = 0.f, d1 = 0.f;
        #pragma unroll
        for (int s = 0; s < 10; ++s) {
            float v = zr[r][s];
            d0 += ulr0[s]*v;
            d1 += ulr1[s]*v;
            zh[l][s*64 + lane] = f2b_(v);
        }
        for (int off = 32; off > 0; off >>= 1) {
            d0 += __shfl_down(d0, off);
            d1 += __shfl_down(d1, off);
        }
        if (lane == 0) {
            bool msk = (shn[l] == 0) && (l != HL-1);
            sc[0][l] = msk ? -1.0e9f : (d0 + c0)*0.05590169943749474f; // 1/sqrt(320)
            sc[1][l] = msk ? -1.0e9f : (d1 + c1)*0.05590169943749474f;
        }
    }
    __syncthreads();
    if (tid < 2) {
        float mx = -3.0e38f;
        for (int m = 0; m < HL; ++m) mx = fmaxf(mx, sc[tid][m]);
        float sum = 0.f;
        for (int m = 0; m < HL; ++m) { float e = expf(sc[tid][m]-mx); aw[tid][m] = e; sum += e; }
        float inv = 1.f/sum;
        for (int m = 0; m < HL; ++m) aw[tid][m] *= inv;
    }
    __syncthreads();
    #pragma unroll
    for (int i = tid; i < 2*DM; i += 256) {
        int h = i / DM, d = i - h*DM;
        float acc = 0.f;
        #pragma unroll
        for (int m = 0; m < HL; ++m) acc += aw[h][m]*b2f_(zh[m][d]);
        wbuf[b*2*DM + i] = acc;
    }
}

// ---------------------------------------------------------------------------
// Row-block GEMM: qn = wbuf @ ZZ + qbias
__global__ __launch_bounds__(256) void k_gemm_qn(const float* __restrict__ A,
                                                 const float* __restrict__ BT,
                                                 const float* __restrict__ bias,
                                                 float* __restrict__ C)
{
    constexpr int K = 2*DM;  // 1280
    __shared__ float As[8*K];   // 40 KB
    int r0 = blockIdx.x*8, tid = threadIdx.x;
    for (int i = tid; i < 8*K; i += 256) As[i] = A[r0*K + i];
    __syncthreads();
    int j = tid & (NF-1), rh = tid >> 7;
    const float* bp = BT + j;
    const float* ap = As + rh*4*K;
    float acc0=0.f, acc1=0.f, acc2=0.f, acc3=0.f;
    for (int d = 0; d < K; ++d) {
        float bv = bp[d*NF];
        acc0 += ap[d]*bv;
        acc1 += ap[K + d]*bv;
        acc2 += ap[2*K + d]*bv;
        acc3 += ap[3*K + d]*bv;
    }
    float bsv = bias[j];
    int rb = r0 + rh*4;
    C[(rb+0)*NF + j] = acc0 + bsv;
    C[(rb+1)*NF + j] = acc1 + bsv;
    C[(rb+2)*NF + j] = acc2 + bsv;
    C[(rb+3)*NF + j] = acc3 + bsv;
}

// Row-block GEMM: gi = lef @ giT + gru_b_ih
__global__ __launch_bounds__(256) void k_gemm_gi(const float* __restrict__ A,
                                                 const float* __restrict__ BT,
                                                 const float* __restrict__ bias,
                                                 float* __restrict__ C)
{
    constexpr int K = DIN;     // 512
    constexpr int N = 3*NF;    // 384
    __shared__ float As[8*K];  // 16 KB
    int r0 = blockIdx.x*8, tid = threadIdx.x;
    for (int i = tid; i < 8*K; i += 256) As[i] = A[r0*K + i];
    __syncthreads();
    int j0 = tid, j1 = tid + 256;
    bool has1 = (j1 < N);
    float a0[8] = {0,0,0,0,0,0,0,0};
    float a1[8] = {0,0,0,0,0,0,0,0};
    for (int d = 0; d < K; ++d) {
        float b0 = BT[d*N + j0];
        float b1 = 0.f;
        if (has1) b1 = BT[d*N + j1];
        #pragma unroll
        for (int r = 0; r < 8; ++r) {
            float av = As[r*K + d];
            a0[r] += av*b0;
            a1[r] += av*b1;
        }
    }
    float bs0 = bias[j0];
    for (int r = 0; r < 8; ++r) C[(r0+r)*N + j0] = a0[r] + bs0;
    if (has1) {
        float bs1 = bias[j1];
        for (int r = 0; r < 8; ++r) C[(r0+r)*N + j1] = a1[r] + bs1;
    }
}

// ---------------------------------------------------------------------------
// K4: attention2 (collapsed) + merge + GRU.  grid 4096, block 128.
__global__ __launch_bounds__(128) void k_attn2(
    const int* __restrict__ nids, const int* __restrict__ hist_nids,
    const int* __restrict__ eidsp, const float* __restrict__ hist_ts,
    const float* __restrict__ node_feat, const float* __restrict__ edge_feat,
    const float* __restrict__ time_w, const float* __restrict__ time_b,
    const float* __restrict__ attn_wq, const float* __restrict__ attn_wk,
    const float* __restrict__ attn_wv,
    const float* __restrict__ merge_w, const float* __restrict__ merge_b,
    const float* __restrict__ qn, const float* __restrict__ gi,
    const float* __restrict__ ghT, const float* __restrict__ gru_b_hh,
    float* __restrict__ hpr_out, float* __restrict__ out)
{
    int b = blockIdx.x, tid = threadIdx.x;
    __shared__ float qns[NF], qh[NF], p[3*NF], nbar[3*NF];
    __shared__ float scl[HL], al[HL];
    __shared__ float ctx2[NF], hpl[NF], nfn[NF];
    __shared__ int   shn[HL], seid[HL];
    __shared__ float sts[HL];

    if (tid < HL) {
        shn[tid]  = hist_nids[b*HL+tid];
        seid[tid] = eidsp[b*HL+tid];
        sts[tid]  = hist_ts[b*HL+tid];
    }
    qns[tid] = qn[b*NF + tid];
    nfn[tid] = node_feat[nids[b]*NF + tid];
    __syncthreads();

    float tlast = sts[HL-1];
    // qh = qn @ attn_wq
    {
        float acc = 0.f;
        for (int d = 0; d < NF; ++d) acc += qns[d]*attn_wq[d*NF + tid];
        qh[tid] = acc;
    }
    __syncthreads();
    // p[d] = sum_j attn_wk[d,j]*qh[j]
    for (int dd = tid; dd < 3*NF; dd += NF) {
        const float4* row4 = (const float4*)(attn_wk + dd*NF);
        float acc = 0.f;
        #pragma unroll
        for (int q4 = 0; q4 < NF/4; ++q4) {
            float4 w4 = row4[q4];
            acc += w4.x*qh[4*q4] + w4.y*qh[4*q4+1] + w4.z*qh[4*q4+2] + w4.w*qh[4*q4+3];
        }
        p[dd] = acc;
    }
    __syncthreads();
    // sc[l] = (p . nb[l]) / sqrt(128), gathering nb[l] straight from global
    int wave = tid >> 6, lane = tid & 63;
    for (int l = wave; l < HL; l += 2) {
        int hn = shn[l], eid = seid[l];
        float dt = tlast - sts[l];
        float acc = 0.f;
        #pragma unroll
        for (int kk = 0; kk < 6; ++kk) {
            int d = lane + 64*kk;
            float v;
            if (d < NF)            v = node_feat[hn*NF + d];
            else if (d < 2*NF)     v = edge_feat[eid*NF + (d-NF)];
            else { int dd = d-2*NF; v = cosf(dt*time_w[dd] + time_b[dd]); }
            acc += p[d]*v;
        }
        for (int off = 32; off > 0; off >>= 1) acc += __shfl_down(acc, off);
        if (lane == 0) {
            bool msk = (hn == 0) && (l != HL-1);
            scl[l] = msk ? -1.0e9f : acc*0.08838834764831845f;  // 1/sqrt(128)
        }
    }
    __syncthreads();
    if (tid == 0) {
        float mx = -3.0e38f;
        for (int m = 0; m < HL; ++m) mx = fmaxf(mx, scl[m]);
        float sum = 0.f;
        for (int m = 0; m < HL; ++m) { float e = expf(scl[m]-mx); al[m] = e; sum += e; }
        float inv = 1.f/sum;
        for (int m = 0; m < HL; ++m) al[m] *= inv;
    }
    __syncthreads();
    // nbar = sum_l a[l]*nb[l]  (second gather pass, L2-warm)
    {
        float twj = time_w[tid], tbj = time_b[tid];
        float an = 0.f, ae = 0.f, at = 0.f;
        #pragma unroll
        for (int l = 0; l < HL; ++l) {
            float a = al[l];
            an += a*node_feat[shn[l]*NF + tid];
            ae += a*edge_feat[seid[l]*NF + tid];
            at += a*cosf((tlast - sts[l])*twj + tbj);
        }
        nbar[tid]       = an;
        nbar[tid+NF]    = ae;
        nbar[tid+2*NF]  = at;
    }
    __syncthreads();
    // ctx2 = nbar @ attn_wv
    {
        float acc = 0.f;
        for (int d = 0; d < 3*NF; ++d) acc += nbar[d]*attn_wv[d*NF + tid];
        ctx2[tid] = acc;
    }
    __syncthreads();
    // h_prev_left
    {
        float acc = merge_b[tid];
        for (int d = 0; d < NF; ++d) acc += ctx2[d]*merge_w[d*NF + tid];
        for (int d = 0; d < NF; ++d) acc += nfn[d]*merge_w[(NF+d)*NF + tid];
        hpl[tid] = tanhf(acc);
    }
    __syncthreads();
    // GRU
    float ghv[3];
    #pragma unroll
    for (int s = 0; s < 3; ++s) {
        int jj = s*NF + tid;
        float acc = gru_b_hh[jj];
        for (int d = 0; d < NF; ++d) acc += hpl[d]*ghT[d*3*NF + jj];
        ghv[s] = acc;
    }
    float gi0 = gi[b*3*NF + tid];
    float gi1 = gi[b*3*NF + NF + tid];
    float gi2 = gi[b*3*NF + 2*NF + tid];
    float r_ = sigmoidf_(gi0 + ghv[0]);
    float z_ = sigmoidf_(gi1 + ghv[1]);
    float n_ = tanhf(gi2 + r_*ghv[2]);
    float hpr = (1.f - z_)*n_ + z_*hpl[tid];
    out[BSZ*NF + b*NF + tid] = hpr;            // h_right
    hpr_out[b*NF + tid] = hpr;                 // for k_ode
    if (tid == 0) out[2*BSZ*NF + b] = tlast;   // hist_ts[:, -1]
}

// ---------------------------------------------------------------------------
// K5: batched RK4 ODE, Q=2 batches/thread (no spill: 128 w-VGPRs + ~40 state).
static __device__ __forceinline__ void ode_eval2(
    const float yin0, const float yin1, const float4* __restrict__ wr, float obj,
    const float rat0, const float rat1, float* __restrict__ yb, int j, int g,
    float* k0, float* k1)
{
    __syncthreads();                      // prior readers of yb done
    yb[(2*g+0)*NF + j] = yin0;
    yb[(2*g+1)*NF + j] = yin1;
    __syncthreads();
    const float4* yA4 = (const float4*)(yb + (2*g+0)*NF);
    const float4* yB4 = (const float4*)(yb + (2*g+1)*NF);
    float a0 = obj, a1 = obj, b0 = 0.f, b1 = 0.f;  // 2 acc chains per batch (ILP)
    #pragma unroll
    for (int q = 0; q < 32; q += 2) {
        float4 w0 = wr[q],   w1 = wr[q+1];
        float4 ya0 = yA4[q], yc0 = yB4[q];
        float4 ya1 = yA4[q+1], yc1 = yB4[q+1];
        a0 += w0.x*ya0.x + w0.y*ya0.y + w0.z*ya0.z + w0.w*ya0.w;
        a1 += w0.x*yc0.x + w0.y*yc0.y + w0.z*yc0.z + w0.w*yc0.w;
        b0 += w1.x*ya1.x + w1.y*ya1.y + w1.z*ya1.z + w1.w*ya1.w;
        b1 += w1.x*yc1.x + w1.y*yc1.y + w1.z*yc1.z + w1.w*yc1.w;
    }
    *k0 = tanhf(a0 + b0)*rat0;
    *k1 = tanhf(a1 + b1)*rat1;
}

__global__ __launch_bounds__(256) void k_ode(
    const float* __restrict__ hpr, const float* __restrict__ hist_ts,
    const float* __restrict__ ode_w, const float* __restrict__ ode_b,
    const float* __restrict__ tnode_w, const float* __restrict__ tnode_b,
    float* __restrict__ out)
{
    __shared__ float yb[4*NF];   // 2 KB, per-batch contiguous rows
    int tid = threadIdx.x;
    int j = tid & (NF-1), g = tid >> 7;     // g in {0,1}, uniform per wave
    int b0 = blockIdx.x*4 + g*2;

    float4 wr[32];
    const float4* owr = (const float4*)(ode_w + j*NF);
    #pragma unroll
    for (int i = 0; i < 32; ++i) wr[i] = owr[i];
    float twj = tnode_w[j], tbj = tnode_b[j], obj = ode_b[j];

    float z0, z1, t00, t01, rat0, rat1;
    {
        float t1a = hist_ts[(b0+0)*HL + (HL-1)];
        float t1b = hist_ts[(b0+1)*HL + (HL-1)];
        t00 = hist_ts[(b0+0)*HL + (HL-2)];
        t01 = hist_ts[(b0+1)*HL + (HL-2)];
        rat0 = t1a - t00; rat1 = t1b - t01;
        z0 = hpr[(b0+0)*NF + j];
        z1 = hpr[(b0+1)*NF + j];
    }

    const float dss = 0.125f;
    #pragma unroll 1
    for (int stp = 0; stp < 8; ++stp) {
        float s0 = stp*dss;
        float teA0 = cosf((s0*rat0 + t00)*twj + tbj);
        float teA1 = cosf((s0*rat1 + t01)*twj + tbj);
        float teB0 = cosf(((s0 + 0.0625f)*rat0 + t00)*twj + tbj);
        float teB1 = cosf(((s0 + 0.0625f)*rat1 + t01)*twj + tbj);
        float teC0 = cosf(((s0 + 0.125f)*rat0 + t00)*twj + tbj);
        float teC1 = cosf(((s0 + 0.125f)*rat1 + t01)*twj + tbj);
        float k10, k11, k20, k21, k30, k31, k40, k41;
        ode_eval2(z0 + teA0,               z1 + teA1,               wr, obj, rat0, rat1, yb, j, g, &k10, &k11);
        ode_eval2(z0 + 0.0625f*k10 + teB0, z1 + 0.0625f*k11 + teB1, wr, obj, rat0, rat1, yb, j, g, &k20, &k21);
        ode_eval2(z0 + 0.0625f*k20 + teB0, z1 + 0.0625f*k21 + teB1, wr, obj, rat0, rat1, yb, j, g, &k30, &k31);
        ode_eval2(z0 + 0.125f*k30 + teC0,  z1 + 0.125f*k31 + teC1,  wr, obj, rat0, rat1, yb, j, g, &k40, &k41);
        z0 += (0.125f/6.f)*(k10 + 2.f*k20 + 2.f*k30 + k40);
        z1 += (0.125f/6.f)*(k11 + 2.f*k21 + 2.f*k31 + k41);
    }
    out[(b0+0)*NF + j] = z0;   // h_left
    out[(b0+1)*NF + j] = z1;
}

// ---------------------------------------------------------------------------
extern "C" void kernel_launch(void* const* d_in, const int* in_sizes, int n_in,
                              void* d_out, int out_size, void* d_ws, size_t ws_size,
                              hipStream_t stream)
{
    (void)in_sizes; (void)n_in; (void)out_size; (void)ws_size;
    const int*   nids      = (const int*)d_in[0];
    const int*   hist_nids = (const int*)d_in[2];
    const int*   aids      = (const int*)d_in[3];
    const int*   eids      = (const int*)d_in[4];
    const float* hist_ts   = (const float*)d_in[5];
    const int*   dirs      = (const int*)d_in[6];
    const float* node_feat = (const float*)d_in[7];
    const float* edge_feat = (const float*)d_in[8];
    const float* anony_emb = (const float*)d_in[9];
    const float* time_w    = (const float*)d_in[10];
    const float* time_b    = (const float*)d_in[11];
    const float* in_proj_w = (const float*)d_in[12];
    const float* in_proj_b = (const float*)d_in[13];
    const float* out_proj_w= (const float*)d_in[14];
    const float* out_proj_b= (const float*)d_in[15];
    const float* outfn_w   = (const float*)d_in[16];
    const float* outfn_b   = (const float*)d_in[17];
    const float* attn_wq   = (const float*)d_in[18];
    const float* attn_wk   = (const float*)d_in[19];
    const float* attn_wv   = (const float*)d_in[20];
    const float* merge_w   = (const float*)d_in[21];
    const float* merge_b   = (const float*)d_in[22];
    const float* gru_w_ih  = (const float*)d_in[23];
    const float* gru_w_hh  = (const float*)d_in[24];
    const float* gru_b_ih  = (const float*)d_in[25];
    const float* gru_b_hh  = (const float*)d_in[26];
    const float* ode_w     = (const float*)d_in[27];
    const float* ode_b     = (const float*)d_in[28];
    const float* tnode_w   = (const float*)d_in[29];
    const float* tnode_b   = (const float*)d_in[30];
    float* out = (float*)d_out;

    float* ws    = (float*)d_ws;
    float* qc    = ws;                   // 640
    float* cc    = ws + 640;             // 2
    float* u     = ws + 768;             // 1280
    float* wbuf  = ws + 2048;            // 4096*1280
    float* lef   = wbuf + BSZ*2*DM;      // 4096*512
    float* qn    = lef + BSZ*DIN;        // 4096*128
    float* gi    = qn + BSZ*NF;          // 4096*384
    float* combT = gi + BSZ*3*NF;        // 640*128
    float* ZZ    = combT + DM*NF;        // 1280*128
    float* qb    = ZZ + 2*DM*NF;         // 128
    float* giT   = qb + NF;              // 512*384
    float* ghT   = giT + DIN*3*NF;       // 128*384
    // hpr aliases wbuf: wbuf's last reader (k_gemm_qn) precedes k_attn2 on
    // the same stream, so reuse is safe.
    float* hpr   = wbuf;                 // 4096*128

    // per-launch constant precomputes
    k_comb<<<DM, NF, 0, stream>>>(outfn_w, out_proj_w, combT);
    k_zz<<<2*DM, NF, 0, stream>>>(in_proj_w, combT, ZZ);
    k_qbias<<<1, NF, 0, stream>>>(outfn_b, out_proj_b, outfn_w, in_proj_b, combT, qb);
    k_transpose<<<960, 256, 0, stream>>>(gru_w_ih, gru_w_hh, giT, ghT);
    k_qc<<<5, 128, 0, stream>>>(time_b, in_proj_w, in_proj_b, qc);
    k_cc<<<1, 128, 0, stream>>>(qc, in_proj_b, cc);
    k_u<<<HL, 64, 0, stream>>>(qc, in_proj_w, u);

    // main pipeline
    k_attn1<<<BSZ, 256, 0, stream>>>(nids, hist_nids, aids, eids, hist_ts, dirs,
                                     node_feat, edge_feat, anony_emb,
                                     time_w, time_b, u, cc, wbuf, lef);
    k_gemm_qn<<<BSZ/8, 256, 0, stream>>>(wbuf, ZZ, qb, qn);
    k_gemm_gi<<<BSZ/8, 256, 0, stream>>>(lef, giT, gru_b_ih, gi);
    k_attn2<<<BSZ, 128, 0, stream>>>(nids, hist_nids, eids, hist_ts,
                                     node_feat, edge_feat, time_w, time_b,
                                     attn_wq, attn_wk, attn_wv, merge_w, merge_b,
                                     qn, gi, ghT, gru_b_hh, hpr, out);
    k_ode<<<BSZ/4, 256, 0, stream>>>(hpr, hist_ts, ode_w, ode_b,
                                     tnode_w, tnode_b, out);
}